// Round 1
// baseline (103.823 us; speedup 1.0000x reference)
//
#include <hip/hip_runtime.h>

#define PAD_IDX 0
#define DIM 16
#define SEQ_L 64
#define ROWS_PER_BLOCK 64
#define THREADS 256
// per-row LDS stride in int4 units: 16 data + 1 pad (16B) to spread banks
#define ROW_STRIDE4 17

__global__ __launch_bounds__(THREADS) void visit_encoder_kernel(
    const int* __restrict__ code_ids,
    const float* __restrict__ emb,
    float* __restrict__ out,
    int B, int n_codes4 /* total int4 count of code_ids */)
{
    __shared__ int4 lcodes[ROWS_PER_BLOCK * ROW_STRIDE4];

    const int t = threadIdx.x;
    const int block_row0 = blockIdx.x * ROWS_PER_BLOCK;

    // ---- Stage this block's codes (64 rows x 64 ints, contiguous) into LDS.
    // Block chunk = 64*64/4 = 1024 int4; 256 threads x 4 int4 each, coalesced.
    const int4* src4 = reinterpret_cast<const int4*>(code_ids);
    const int base4 = blockIdx.x * (ROWS_PER_BLOCK * SEQ_L / 4);
    #pragma unroll
    for (int k = 0; k < 4; ++k) {
        int j = t + THREADS * k;                 // 0..1023
        int gj = base4 + j;
        if (gj >= n_codes4) gj = n_codes4 - 1;   // tail safety (no-op for B=200000)
        int4 v = src4[gj];
        int rr = j >> 4;                          // row within block
        int ll = j & 15;                          // int4 within row
        lcodes[rr * ROW_STRIDE4 + ll] = v;
    }
    __syncthreads();

    // ---- Compute: thread (r, d4) owns float4 d4 of row r.
    const int r  = t >> 2;     // 0..63
    const int d4 = t & 3;      // 0..3
    // per-thread base: emb row stride = 4 float4; addr = base + c*64B
    const float4* ebase = reinterpret_cast<const float4*>(emb) + d4;

    float4 acc = make_float4(0.f, 0.f, 0.f, 0.f);
    int cnt = 0;

    #pragma unroll
    for (int l4 = 0; l4 < 16; ++l4) {
        int4 c4 = lcodes[r * ROW_STRIDE4 + l4];
        int cs[4] = {c4.x, c4.y, c4.z, c4.w};
        #pragma unroll
        for (int u = 0; u < 4; ++u) {
            int c = cs[u];
            float4 e = ebase[(size_t)c * 4];      // v_lshl_add_u64 + dwordx4
            acc.x += e.x; acc.y += e.y; acc.z += e.z; acc.w += e.w;
            ++cnt;
            if (__builtin_expect(c == PAD_IDX, 0)) {
                // rare fixup (P ~ 1e-5): undo the pad contribution
                acc.x -= e.x; acc.y -= e.y; acc.z -= e.z; acc.w -= e.w;
                --cnt;
            }
        }
    }

    const int row = block_row0 + r;
    if (row < B) {
        float denom = fmaxf((float)cnt, 1.0f);
        float inv = 1.0f / denom;
        float4 o;
        o.x = acc.x * inv; o.y = acc.y * inv; o.z = acc.z * inv; o.w = acc.w * inv;
        reinterpret_cast<float4*>(out)[(size_t)row * 4 + d4] = o;
    }
}

extern "C" void kernel_launch(void* const* d_in, const int* in_sizes, int n_in,
                              void* d_out, int out_size, void* d_ws, size_t ws_size,
                              hipStream_t stream) {
    const int*   code_ids = (const int*)d_in[0];
    const float* emb      = (const float*)d_in[1];
    float*       out      = (float*)d_out;

    const int total_codes = in_sizes[0];        // B * L
    const int B = total_codes / SEQ_L;
    const int n_codes4 = total_codes / 4;
    const int grid = (B + ROWS_PER_BLOCK - 1) / ROWS_PER_BLOCK;

    visit_encoder_kernel<<<dim3(grid), dim3(THREADS), 0, stream>>>(
        code_ids, emb, out, B, n_codes4);
}

// Round 2
// 101.016 us; speedup vs baseline: 1.0278x; 1.0278x over previous
//
#include <hip/hip_runtime.h>

#define PAD_IDX 0
#define DIM 16
#define SEQ_L 64
#define ROWS_PER_BLOCK 64
#define THREADS 256
// per-row LDS stride in int4 units: 16 data + 1 pad (16B) to spread banks
#define ROW_STRIDE4 17

__global__ __launch_bounds__(THREADS) void visit_encoder_kernel(
    const int* __restrict__ code_ids,
    const float* __restrict__ emb,
    float* __restrict__ out,
    int B, int n_codes4 /* total int4 count of code_ids */)
{
    __shared__ int4 lcodes[ROWS_PER_BLOCK * ROW_STRIDE4];

    const int t = threadIdx.x;
    const int block_row0 = blockIdx.x * ROWS_PER_BLOCK;

    // ---- Stage this block's codes (64 rows x 64 ints, contiguous) into LDS.
    const int4* src4 = reinterpret_cast<const int4*>(code_ids);
    const int base4 = blockIdx.x * (ROWS_PER_BLOCK * SEQ_L / 4);
    #pragma unroll
    for (int k = 0; k < 4; ++k) {
        int j = t + THREADS * k;                 // 0..1023
        int gj = base4 + j;
        if (gj >= n_codes4) gj = n_codes4 - 1;   // tail safety (no-op for B=200000)
        int4 v = src4[gj];
        int rr = j >> 4;                          // row within block
        int ll = j & 15;                          // int4 within row
        lcodes[rr * ROW_STRIDE4 + ll] = v;
    }
    __syncthreads();

    // ---- Compute: thread (r, d4) owns float4 d4 of row r.
    const int r  = t >> 2;     // 0..63
    const int d4 = t & 3;      // 0..3
    const float4* ebase = reinterpret_cast<const float4*>(emb) + d4;

    float4 acc = make_float4(0.f, 0.f, 0.f, 0.f);
    int cnt = 0;

    // Batch 8 gathers in flight, then branchless masked accumulate.
    #pragma unroll
    for (int l4 = 0; l4 < 16; l4 += 2) {
        int4 ca = lcodes[r * ROW_STRIDE4 + l4];
        int4 cb = lcodes[r * ROW_STRIDE4 + l4 + 1];
        int cs[8] = {ca.x, ca.y, ca.z, ca.w, cb.x, cb.y, cb.z, cb.w};
        float4 e[8];
        #pragma unroll
        for (int u = 0; u < 8; ++u) {
            e[u] = ebase[(size_t)cs[u] * 4];      // 8 independent dwordx4 in flight
        }
        #pragma unroll
        for (int u = 0; u < 8; ++u) {
            float m = (cs[u] != PAD_IDX) ? 1.0f : 0.0f;
            acc.x = fmaf(e[u].x, m, acc.x);
            acc.y = fmaf(e[u].y, m, acc.y);
            acc.z = fmaf(e[u].z, m, acc.z);
            acc.w = fmaf(e[u].w, m, acc.w);
            cnt += (cs[u] != PAD_IDX);
        }
    }

    const int row = block_row0 + r;
    if (row < B) {
        float denom = fmaxf((float)cnt, 1.0f);
        float inv = 1.0f / denom;
        float4 o;
        o.x = acc.x * inv; o.y = acc.y * inv; o.z = acc.z * inv; o.w = acc.w * inv;
        reinterpret_cast<float4*>(out)[(size_t)row * 4 + d4] = o;
    }
}

extern "C" void kernel_launch(void* const* d_in, const int* in_sizes, int n_in,
                              void* d_out, int out_size, void* d_ws, size_t ws_size,
                              hipStream_t stream) {
    const int*   code_ids = (const int*)d_in[0];
    const float* emb      = (const float*)d_in[1];
    float*       out      = (float*)d_out;

    const int total_codes = in_sizes[0];        // B * L
    const int B = total_codes / SEQ_L;
    const int n_codes4 = total_codes / 4;
    const int grid = (B + ROWS_PER_BLOCK - 1) / ROWS_PER_BLOCK;

    visit_encoder_kernel<<<dim3(grid), dim3(THREADS), 0, stream>>>(
        code_ids, emb, out, B, n_codes4);
}

// Round 3
// 68.584 us; speedup vs baseline: 1.5138x; 1.4729x over previous
//
#include <hip/hip_runtime.h>
#include <hip/hip_bf16.h>

#define PAD_IDX 0
#define DIM 16
#define SEQ_L 64
#define ROWS_PER_BLOCK 64
#define THREADS 256
// per-row LDS stride in int4 units: 16 data + 1 pad (16B) to spread banks
#define ROW_STRIDE4 17

__device__ __forceinline__ float bf16_lo(unsigned int w) {
    return __uint_as_float(w << 16);
}
__device__ __forceinline__ float bf16_hi(unsigned int w) {
    return __uint_as_float(w & 0xffff0000u);
}

// ---- Pass 1: convert fp32 table -> packed bf16 table in workspace.
__global__ __launch_bounds__(THREADS) void convert_bf16_kernel(
    const float* __restrict__ emb, ushort* __restrict__ tab, int n /* elements */)
{
    int i4 = (blockIdx.x * THREADS + threadIdx.x) * 4;
    if (i4 + 3 < n) {
        float4 v = *reinterpret_cast<const float4*>(emb + i4);
        ushort4 o;
        o.x = __bfloat16_as_ushort(__float2bfloat16(v.x));
        o.y = __bfloat16_as_ushort(__float2bfloat16(v.y));
        o.z = __bfloat16_as_ushort(__float2bfloat16(v.z));
        o.w = __bfloat16_as_ushort(__float2bfloat16(v.w));
        *reinterpret_cast<ushort4*>(tab + i4) = o;
    } else if (i4 < n) {
        for (int k = i4; k < n; ++k)
            tab[k] = __bfloat16_as_ushort(__float2bfloat16(emb[k]));
    }
}

// ---- Pass 2: gather from bf16 table (L2-resident), masked mean.
__global__ __launch_bounds__(THREADS) void visit_encoder_bf16_kernel(
    const int* __restrict__ code_ids,
    const uint2* __restrict__ tab,   // bf16 table, row = 32B = 4 x uint2
    float* __restrict__ out,
    int B, int n_codes4)
{
    __shared__ int4 lcodes[ROWS_PER_BLOCK * ROW_STRIDE4];

    const int t = threadIdx.x;
    const int block_row0 = blockIdx.x * ROWS_PER_BLOCK;

    const int4* src4 = reinterpret_cast<const int4*>(code_ids);
    const int base4 = blockIdx.x * (ROWS_PER_BLOCK * SEQ_L / 4);
    #pragma unroll
    for (int k = 0; k < 4; ++k) {
        int j = t + THREADS * k;
        int gj = base4 + j;
        if (gj >= n_codes4) gj = n_codes4 - 1;
        int4 v = src4[gj];
        lcodes[(j >> 4) * ROW_STRIDE4 + (j & 15)] = v;
    }
    __syncthreads();

    const int r  = t >> 2;     // 0..63
    const int d4 = t & 3;      // 0..3 -> dims 4*d4 .. 4*d4+3
    const uint2* tbase = tab + d4;   // element stride per code row = 4 uint2

    float4 acc = make_float4(0.f, 0.f, 0.f, 0.f);
    int cnt = 0;

    #pragma unroll
    for (int l4 = 0; l4 < 16; l4 += 2) {
        int4 ca = lcodes[r * ROW_STRIDE4 + l4];
        int4 cb = lcodes[r * ROW_STRIDE4 + l4 + 1];
        int cs[8] = {ca.x, ca.y, ca.z, ca.w, cb.x, cb.y, cb.z, cb.w};
        uint2 e[8];
        #pragma unroll
        for (int u = 0; u < 8; ++u) {
            e[u] = tbase[(size_t)cs[u] * 4];   // 8B dwordx2, 8 in flight
        }
        #pragma unroll
        for (int u = 0; u < 8; ++u) {
            float m = (cs[u] != PAD_IDX) ? 1.0f : 0.0f;
            acc.x = fmaf(bf16_lo(e[u].x), m, acc.x);
            acc.y = fmaf(bf16_hi(e[u].x), m, acc.y);
            acc.z = fmaf(bf16_lo(e[u].y), m, acc.z);
            acc.w = fmaf(bf16_hi(e[u].y), m, acc.w);
            cnt += (cs[u] != PAD_IDX);
        }
    }

    const int row = block_row0 + r;
    if (row < B) {
        float inv = 1.0f / fmaxf((float)cnt, 1.0f);
        float4 o;
        o.x = acc.x * inv; o.y = acc.y * inv; o.z = acc.z * inv; o.w = acc.w * inv;
        reinterpret_cast<float4*>(out)[(size_t)row * 4 + d4] = o;
    }
}

// ---- Fallback: direct fp32 gather (R2 kernel) if ws too small.
__global__ __launch_bounds__(THREADS) void visit_encoder_f32_kernel(
    const int* __restrict__ code_ids,
    const float* __restrict__ emb,
    float* __restrict__ out,
    int B, int n_codes4)
{
    __shared__ int4 lcodes[ROWS_PER_BLOCK * ROW_STRIDE4];
    const int t = threadIdx.x;
    const int block_row0 = blockIdx.x * ROWS_PER_BLOCK;
    const int4* src4 = reinterpret_cast<const int4*>(code_ids);
    const int base4 = blockIdx.x * (ROWS_PER_BLOCK * SEQ_L / 4);
    #pragma unroll
    for (int k = 0; k < 4; ++k) {
        int j = t + THREADS * k;
        int gj = base4 + j;
        if (gj >= n_codes4) gj = n_codes4 - 1;
        int4 v = src4[gj];
        lcodes[(j >> 4) * ROW_STRIDE4 + (j & 15)] = v;
    }
    __syncthreads();

    const int r  = t >> 2;
    const int d4 = t & 3;
    const float4* ebase = reinterpret_cast<const float4*>(emb) + d4;
    float4 acc = make_float4(0.f, 0.f, 0.f, 0.f);
    int cnt = 0;
    #pragma unroll
    for (int l4 = 0; l4 < 16; l4 += 2) {
        int4 ca = lcodes[r * ROW_STRIDE4 + l4];
        int4 cb = lcodes[r * ROW_STRIDE4 + l4 + 1];
        int cs[8] = {ca.x, ca.y, ca.z, ca.w, cb.x, cb.y, cb.z, cb.w};
        float4 e[8];
        #pragma unroll
        for (int u = 0; u < 8; ++u) e[u] = ebase[(size_t)cs[u] * 4];
        #pragma unroll
        for (int u = 0; u < 8; ++u) {
            float m = (cs[u] != PAD_IDX) ? 1.0f : 0.0f;
            acc.x = fmaf(e[u].x, m, acc.x);
            acc.y = fmaf(e[u].y, m, acc.y);
            acc.z = fmaf(e[u].z, m, acc.z);
            acc.w = fmaf(e[u].w, m, acc.w);
            cnt += (cs[u] != PAD_IDX);
        }
    }
    const int row = block_row0 + r;
    if (row < B) {
        float inv = 1.0f / fmaxf((float)cnt, 1.0f);
        float4 o;
        o.x = acc.x * inv; o.y = acc.y * inv; o.z = acc.z * inv; o.w = acc.w * inv;
        reinterpret_cast<float4*>(out)[(size_t)row * 4 + d4] = o;
    }
}

extern "C" void kernel_launch(void* const* d_in, const int* in_sizes, int n_in,
                              void* d_out, int out_size, void* d_ws, size_t ws_size,
                              hipStream_t stream) {
    const int*   code_ids = (const int*)d_in[0];
    const float* emb      = (const float*)d_in[1];
    float*       out      = (float*)d_out;

    const int total_codes = in_sizes[0];        // B * L
    const int B = total_codes / SEQ_L;
    const int n_codes4 = total_codes / 4;
    const int emb_elems = in_sizes[1];          // NUM_CODES * DIM
    const int grid = (B + ROWS_PER_BLOCK - 1) / ROWS_PER_BLOCK;

    const size_t tab_bytes = (size_t)emb_elems * sizeof(ushort);
    if (ws_size >= tab_bytes) {
        ushort* tab = (ushort*)d_ws;
        int n4 = (emb_elems + 3) / 4;
        convert_bf16_kernel<<<dim3((n4 + THREADS - 1) / THREADS), dim3(THREADS), 0, stream>>>(
            emb, tab, emb_elems);
        visit_encoder_bf16_kernel<<<dim3(grid), dim3(THREADS), 0, stream>>>(
            code_ids, (const uint2*)tab, out, B, n_codes4);
    } else {
        visit_encoder_f32_kernel<<<dim3(grid), dim3(THREADS), 0, stream>>>(
            code_ids, emb, out, B, n_codes4);
    }
}